// Round 12
// baseline (813.786 us; speedup 1.0000x reference)
//
#include <hip/hip_runtime.h>
#include <stdint.h>

// NNAKF round 12: chain surgery on the Kalman wave.
// 576 threads = 9 waves. w0 = PURE Kalman wave (no recurrent GEMM): af -> fc
// -> sigma -> DPP-Qdot -> update -> predict -> In. Waves 1-8: 4 gate-tiles
// (16 MFMA) + 64 pointwise cells each (exact cover of 32 tiles / 512 cells).
// sigma LDS round-trip replaced by in-wave DPP: 3 quad_perm broadcasts +
// 16 FMA partials + rotate-add (row_ror:4, row_ror:8) = Q_adapt col sums
// with zero LDS hops. 2 barriers/step (h publish, In publish).

#define DTc  0.1f
#define Q0V  0.01f      // PROCESS_NOISE_STD^2
#define RV   0.25f      // MEAS_NOISE_STD^2

typedef __bf16 bf16x8 __attribute__((ext_vector_type(8)));
typedef float  f32x4  __attribute__((ext_vector_type(4)));

__device__ __forceinline__ unsigned short f2bf(float f) {
    union { float f; unsigned int ui; } c; c.f = f;
    unsigned int u = c.ui;
    return (unsigned short)((u + 0x7FFFu + ((u >> 16) & 1u)) >> 16);   // RNE
}
__device__ __forceinline__ bf16x8 cvt8(float4 a, float4 b) {
    union { unsigned short us[8]; bf16x8 v; } r;
    r.us[0] = f2bf(a.x); r.us[1] = f2bf(a.y); r.us[2] = f2bf(a.z); r.us[3] = f2bf(a.w);
    r.us[4] = f2bf(b.x); r.us[5] = f2bf(b.y); r.us[6] = f2bf(b.z); r.us[7] = f2bf(b.w);
    return r.v;
}
__device__ __forceinline__ float rcpf(float x)  { return __builtin_amdgcn_rcpf(x); }
__device__ __forceinline__ float sigmf(float x) { return rcpf(1.0f + __expf(-x)); }
__device__ __forceinline__ float tanhf_(float x){ return 1.0f - 2.0f * rcpf(__expf(2.0f * x) + 1.0f); }

#define QP_ROT2  0x4E    // quad_perm [2,3,0,1]
#define QP_BC0   0x00    // quad broadcast lane 0
#define QP_BC1   0x55    // quad broadcast lane 1
#define QP_BC2   0xAA    // quad broadcast lane 2
#define QP_BC3   0xFF    // quad broadcast lane 3
#define ROW_ROR4 0x124   // row rotate by 4 (within 16-lane row)
#define ROW_ROR8 0x128   // row rotate by 8
template<int CTRL>
__device__ __forceinline__ float dppf(float x) {
    return __builtin_bit_cast(float,
        __builtin_amdgcn_update_dpp(0, __builtin_bit_cast(int, x), CTRL, 0xF, 0xF, true));
}

__global__ __launch_bounds__(576, 1) void nnakf_kernel(
    const float* __restrict__ meas,   // [1024][512][2] f32
    const float* __restrict__ Qt,     // [10][4][4]
    const float* __restrict__ Wih,    // [512][2]
    const float* __restrict__ Whh,    // [512][128]
    const float* __restrict__ bih,    // [512]
    const float* __restrict__ bhh,    // [512]
    const float* __restrict__ Wfc,    // [10][128]
    const float* __restrict__ bfc,    // [10]
    float* __restrict__ out)          // [1024][512][4] f32
{
    __shared__ float          meas_s[4 * 1024];   // [b][t*2+c]
    __shared__ unsigned short hbuf[640];          // h bf16, [b] stride 160
    __shared__ float2         inbuf[4];           // In per batch

    const int tid  = threadIdx.x;
    const int w    = tid >> 6;          // wave 0..8 (0 = Kalman wave)
    const int lane = tid & 63;
    const int idx  = lane & 15;
    const int q    = lane >> 4;         // batch
    const int j    = lane & 3;          // Kalman column (w0)
    const int a4   = idx >> 2;          // quad index within 16-lane group (w0)
    const int bg0  = blockIdx.x * 4;
    const int wl   = (w == 0) ? 0 : (w - 1);   // LSTM wave index 0..7
    const int hh   = wl * 16 + idx;     // this thread's LSTM cell (waves 1-8)

    // ---- cooperative meas load ----
    {
        const float4* g4 = (const float4*)(meas + (size_t)bg0 * 1024);
        float4* ms4 = (float4*)meas_s;
        for (int k = tid; k < 1024; k += 576) ms4[k] = g4[k];
    }

    // LSTM-wave weights (w0 loads wave-1's copy; unused there, uniform code)
    bf16x8 wf[4][4];
    f32x4  biasC[4];
    float2 wihr[4];
    const float4* whh4 = (const float4*)Whh;
    #pragma unroll
    for (int g = 0; g < 4; ++g) {
        const int n = (g << 7) + hh;
        const float bb = bih[n] + bhh[n];
        biasC[g] = (f32x4){bb, bb, bb, bb};
        wihr[g] = ((const float2*)Wih)[n];
        #pragma unroll
        for (int s = 0; s < 4; ++s) {
            float4 u0 = whh4[n * 32 + s * 8 + q * 2];
            float4 u1 = whh4[n * 32 + s * 8 + q * 2 + 1];
            wf[g][s] = cvt8(u0, u1);   // B[k=s*32+q*8+e][n]
        }
    }
    // Kalman-wave weights
    bf16x8 fcf[4];
    #pragma unroll
    for (int s = 0; s < 4; ++s) {
        float4 u0 = make_float4(0.f, 0.f, 0.f, 0.f), u1 = u0;
        if (idx < 10) {
            u0 = ((const float4*)Wfc)[idx * 32 + s * 8 + q * 2];
            u1 = ((const float4*)Wfc)[idx * 32 + s * 8 + q * 2 + 1];
        }
        fcf[s] = cvt8(u0, u1);
    }
    const float bfc_r = (idx < 10) ? bfc[idx] : 0.0f;
    // Qt coefficients for DPP-Qdot: qreg2[c][r] = Qt[4*a4+c][r][j] (0 if n>=10)
    float qreg2[4][4];
    #pragma unroll
    for (int c = 0; c < 4; ++c) {
        const int n = 4 * a4 + c;
        #pragma unroll
        for (int r = 0; r < 4; ++r)
            qreg2[c][r] = (n < 10) ? Qt[n * 16 + r * 4 + j] : 0.0f;
    }

    // ---- persistent state (Kalman parts meaningful on w0 only) ----
    float P0 = (j == 0) ? 1.f : 0.f, P1 = (j == 1) ? 1.f : 0.f;
    float P2 = (j == 2) ? 1.f : 0.f, P3 = (j == 3) ? 1.f : 0.f;
    float x0 = 0.f, x1 = 0.f, x2 = 0.f, x3 = 0.f;
    float cst = 0.f;
    float ppc0, ppc1, ppc2, ppc3, xp0, xp1, inn0, inn1, In0, In1;
    f32x4 acc[4];

    #define PREDICT(TT)                                                          \
    {                                                                            \
        const float fp0 = P0 + DTc * P2, fp1 = P1 + DTc * P3;                    \
        const float d0 = dppf<QP_ROT2>(P0), d1 = dppf<QP_ROT2>(P1);              \
        const float d2 = dppf<QP_ROT2>(P2), d3 = dppf<QP_ROT2>(P3);              \
        const float fq0 = d0 + DTc * d2, fq1 = d1 + DTc * d3;                    \
        const bool jl2 = (j < 2);                                                \
        ppc0 = fp0 + (jl2 ? DTc * fq0 : 0.f) + ((j == 0) ? Q0V : 0.f);           \
        ppc1 = fp1 + (jl2 ? DTc * fq1 : 0.f) + ((j == 1) ? Q0V : 0.f);           \
        ppc2 = P2  + (jl2 ? DTc * d2  : 0.f) + ((j == 2) ? Q0V : 0.f);           \
        ppc3 = P3  + (jl2 ? DTc * d3  : 0.f) + ((j == 3) ? Q0V : 0.f);           \
        xp0 = x0 + DTc * x2; xp1 = x1 + DTc * x3;                                \
        const float2 zz = *(const float2*)&meas_s[q * 1024 + 2 * (TT)];          \
        inn0 = zz.x - xp0; inn1 = zz.y - xp1;                                    \
        const float s000 = dppf<QP_BC0>(ppc0) + RV;                              \
        const float s011 = dppf<QP_BC1>(ppc1) + RV;                              \
        In0 = inn0 * inn0 * rcpf(s000);                                          \
        In1 = inn1 * inn1 * rcpf(s011);                                          \
    }

    __syncthreads();   // meas_s ready

    if (w == 0) {
        PREDICT(0)
        if (idx == 0) inbuf[q] = make_float2(In0, In1);
    }
    #pragma unroll
    for (int g = 0; g < 4; ++g) acc[g] = biasC[g];   // h(-1)=0 -> gates = bias

    __syncthreads();   // inbuf(0) ready

    for (int t = 0; t < 512; ++t) {
        // ======== segment A: pointwise LSTM(t) on waves 1-8 ==================
        if (w > 0) {
            const float2 inq = inbuf[q];
            float pre[4];
            #pragma unroll
            for (int g = 0; g < 4; ++g)
                pre[g] = acc[g][0] + inq.x * wihr[g].x + inq.y * wihr[g].y;
            const float cn = sigmf(pre[1]) * cst + sigmf(pre[0]) * tanhf_(pre[2]);
            const float hn = sigmf(pre[3]) * tanhf_(cn);
            cst = cn;
            hbuf[q * 160 + hh] = f2bf(hn);
        }
        __syncthreads();   // B1: h(t) published

        // ======== segment B: GEMM (w1-8)  ||  Kalman tail (w0) ===============
        bf16x8 af[4];
        #pragma unroll
        for (int s = 0; s < 4; ++s)
            af[s] = __builtin_bit_cast(bf16x8,
                        *(const uint4*)&hbuf[(idx >> 2) * 160 + s * 32 + q * 8]);

        if (w == 0) {
            // fc GEMM -> sigma (own batch q, n = idx)
            f32x4 f0 = (f32x4){0.f, 0.f, 0.f, 0.f};
            f32x4 f1 = (f32x4){0.f, 0.f, 0.f, 0.f};
            f0 = __builtin_amdgcn_mfma_f32_16x16x32_bf16(af[0], fcf[0], f0, 0, 0, 0);
            f1 = __builtin_amdgcn_mfma_f32_16x16x32_bf16(af[1], fcf[1], f1, 0, 0, 0);
            f0 = __builtin_amdgcn_mfma_f32_16x16x32_bf16(af[2], fcf[2], f0, 0, 0, 0);
            f1 = __builtin_amdgcn_mfma_f32_16x16x32_bf16(af[3], fcf[3], f1, 0, 0, 0);
            const f32x4 facc = f0 + f1;
            const float sg = (idx < 10) ? sigmf(facc[0] + bfc_r) : 0.0f;

            // DPP-Qdot: quad broadcasts -> partials -> rotate-add over quads
            const float s0 = dppf<QP_BC0>(sg), s1 = dppf<QP_BC1>(sg);
            const float s2 = dppf<QP_BC2>(sg), s3 = dppf<QP_BC3>(sg);
            float p0 = s0 * qreg2[0][0] + s1 * qreg2[1][0] + s2 * qreg2[2][0] + s3 * qreg2[3][0];
            float p1 = s0 * qreg2[0][1] + s1 * qreg2[1][1] + s2 * qreg2[2][1] + s3 * qreg2[3][1];
            float p2 = s0 * qreg2[0][2] + s1 * qreg2[1][2] + s2 * qreg2[2][2] + s3 * qreg2[3][2];
            float p3 = s0 * qreg2[0][3] + s1 * qreg2[1][3] + s2 * qreg2[2][3] + s3 * qreg2[3][3];
            p0 += dppf<ROW_ROR4>(p0); p1 += dppf<ROW_ROR4>(p1);
            p2 += dppf<ROW_ROR4>(p2); p3 += dppf<ROW_ROR4>(p3);
            p0 += dppf<ROW_ROR8>(p0); p1 += dppf<ROW_ROR8>(p1);
            p2 += dppf<ROW_ROR8>(p2); p3 += dppf<ROW_ROR8>(p3);

            const float pc0 = ppc0 + p0;   // P_pred[:,j]
            const float pc1 = ppc1 + p1;
            const float pc2 = ppc2 + p2;
            const float pc3 = ppc3 + p3;

            // Kalman update (K eliminated)
            const float ph00 = dppf<QP_BC0>(pc0), ph01 = dppf<QP_BC1>(pc0);
            const float ph10 = dppf<QP_BC0>(pc1), ph11 = dppf<QP_BC1>(pc1);
            const float ph20 = dppf<QP_BC0>(pc2), ph21 = dppf<QP_BC1>(pc2);
            const float ph30 = dppf<QP_BC0>(pc3), ph31 = dppf<QP_BC1>(pc3);
            const float s00 = ph00 + RV, s01 = ph01, s10 = ph10, s11 = ph11 + RV;
            const float rdet = rcpf(s00 * s11 - s01 * s10);
            const float u0 = rdet * (s11 * inn0 - s01 * inn1);
            const float u1 = rdet * (s00 * inn1 - s10 * inn0);
            x0 = xp0 + ph00 * u0 + ph01 * u1;
            x1 = xp1 + ph10 * u0 + ph11 * u1;
            x2 = x2  + ph20 * u0 + ph21 * u1;
            x3 = x3  + ph30 * u0 + ph31 * u1;
            const float w0r = rdet * (s11 * pc0 - s01 * pc1);
            const float w1r = rdet * (s00 * pc1 - s10 * pc0);
            P0 = pc0 - ph00 * w0r - ph01 * w1r;
            P1 = pc1 - ph10 * w0r - ph11 * w1r;
            P2 = pc2 - ph20 * w0r - ph21 * w1r;
            P3 = pc3 - ph30 * w0r - ph31 * w1r;
            if (idx == 0) {
                float4* o = (float4*)out;
                o[(size_t)(bg0 + q) * 512 + t] = make_float4(x0, x1, x2, x3);
            }
            const int tn = (t < 511) ? t + 1 : 511;
            PREDICT(tn)
            if (idx == 0) inbuf[q] = make_float2(In0, In1);
        } else {
            // recurrent GEMM(t+1), bias in C of first MFMA
            #pragma unroll
            for (int g = 0; g < 4; ++g)
                acc[g] = __builtin_amdgcn_mfma_f32_16x16x32_bf16(af[0], wf[g][0], biasC[g], 0, 0, 0);
            #pragma unroll
            for (int s = 1; s < 4; ++s)
                #pragma unroll
                for (int g = 0; g < 4; ++g)
                    acc[g] = __builtin_amdgcn_mfma_f32_16x16x32_bf16(af[s], wf[g][s], acc[g], 0, 0, 0);
        }
        __syncthreads();   // B2: In(t+1) published; hbuf free for rewrite
    }
}

extern "C" void kernel_launch(void* const* d_in, const int* in_sizes, int n_in,
                              void* d_out, int out_size, void* d_ws, size_t ws_size,
                              hipStream_t stream) {
    (void)in_sizes; (void)n_in; (void)out_size; (void)d_ws; (void)ws_size;
    nnakf_kernel<<<256, 576, 0, stream>>>(
        (const float*)d_in[0],  // measurements
        (const float*)d_in[1],  // Q_tilde
        (const float*)d_in[2],  // W_ih
        (const float*)d_in[3],  // W_hh
        (const float*)d_in[4],  // b_ih
        (const float*)d_in[5],  // b_hh
        (const float*)d_in[6],  // W_fc
        (const float*)d_in[7],  // b_fc
        (float*)d_out);
}

// Round 13
// 464.465 us; speedup vs baseline: 1.7521x; 1.7521x over previous
//
#include <hip/hip_runtime.h>
#include <stdint.h>

// NNAKF round 13: r11 container (512 thr / 8 waves, VGPR-safe) + r12's
// DPP-Qdot chain surgery. r12's 9-wave shape cut VGPR to 84 -> wf spilled to
// scratch (FETCH 26MB/WRITE 55MB = HBM streaming) -> regression. Here: every
// wave does 4 gate-tiles GEMM + 1 pointwise cell; w0 additionally runs the
// Kalman tail with sigma distributed via in-wave DPP (4 quad-broadcasts +
// 16 FMA + row_ror:4/8 rotate-adds) -- sigma LDS round-trip deleted.
// 2 barriers/step (h publish, In publish).

#define DTc  0.1f
#define Q0V  0.01f      // PROCESS_NOISE_STD^2
#define RV   0.25f      // MEAS_NOISE_STD^2

typedef __bf16 bf16x8 __attribute__((ext_vector_type(8)));
typedef float  f32x4  __attribute__((ext_vector_type(4)));

__device__ __forceinline__ unsigned short f2bf(float f) {
    union { float f; unsigned int ui; } c; c.f = f;
    unsigned int u = c.ui;
    return (unsigned short)((u + 0x7FFFu + ((u >> 16) & 1u)) >> 16);   // RNE
}
__device__ __forceinline__ bf16x8 cvt8(float4 a, float4 b) {
    union { unsigned short us[8]; bf16x8 v; } r;
    r.us[0] = f2bf(a.x); r.us[1] = f2bf(a.y); r.us[2] = f2bf(a.z); r.us[3] = f2bf(a.w);
    r.us[4] = f2bf(b.x); r.us[5] = f2bf(b.y); r.us[6] = f2bf(b.z); r.us[7] = f2bf(b.w);
    return r.v;
}
__device__ __forceinline__ float rcpf(float x)  { return __builtin_amdgcn_rcpf(x); }
__device__ __forceinline__ float sigmf(float x) { return rcpf(1.0f + __expf(-x)); }
__device__ __forceinline__ float tanhf_(float x){ return 1.0f - 2.0f * rcpf(__expf(2.0f * x) + 1.0f); }

#define QP_ROT2  0x4E    // quad_perm [2,3,0,1]
#define QP_BC0   0x00    // quad broadcast lane 0
#define QP_BC1   0x55    // quad broadcast lane 1
#define QP_BC2   0xAA    // quad broadcast lane 2
#define QP_BC3   0xFF    // quad broadcast lane 3
#define ROW_ROR4 0x124   // row rotate by 4 (16-lane row)
#define ROW_ROR8 0x128   // row rotate by 8
template<int CTRL>
__device__ __forceinline__ float dppf(float x) {
    return __builtin_bit_cast(float,
        __builtin_amdgcn_update_dpp(0, __builtin_bit_cast(int, x), CTRL, 0xF, 0xF, true));
}

__global__ __launch_bounds__(512, 2) void nnakf_kernel(
    const float* __restrict__ meas,   // [1024][512][2] f32
    const float* __restrict__ Qt,     // [10][4][4]
    const float* __restrict__ Wih,    // [512][2]
    const float* __restrict__ Whh,    // [512][128]
    const float* __restrict__ bih,    // [512]
    const float* __restrict__ bhh,    // [512]
    const float* __restrict__ Wfc,    // [10][128]
    const float* __restrict__ bfc,    // [10]
    float* __restrict__ out)          // [1024][512][4] f32
{
    __shared__ float          meas_s[4 * 1024];   // [b][t*2+c]
    __shared__ unsigned short hbuf[640];          // h bf16, [b] stride 160
    __shared__ float2         inbuf[4];           // In per batch

    const int tid  = threadIdx.x;
    const int w    = tid >> 6;          // wave 0..7 (0 = Kalman wave)
    const int lane = tid & 63;
    const int idx  = lane & 15;
    const int q    = lane >> 4;         // batch
    const int j    = lane & 3;          // Kalman column (w0)
    const int a4   = idx >> 2;          // quad index within 16-lane group (w0)
    const int bg0  = blockIdx.x * 4;
    const int hh   = w * 16 + idx;      // this thread's LSTM cell

    // ---- cooperative meas load ----
    {
        const float4* g4 = (const float4*)(meas + (size_t)bg0 * 1024);
        float4* ms4 = (float4*)meas_s;
        for (int k = tid; k < 1024; k += 512) ms4[k] = g4[k];
    }

    // W_hh B-fragments: tile g covers n = g*128 + hh
    bf16x8 wf[4][4];
    f32x4  biasC[4];
    float2 wihr[4];
    const float4* whh4 = (const float4*)Whh;
    #pragma unroll
    for (int g = 0; g < 4; ++g) {
        const int n = (g << 7) + hh;
        const float bb = bih[n] + bhh[n];
        biasC[g] = (f32x4){bb, bb, bb, bb};
        wihr[g] = ((const float2*)Wih)[n];
        #pragma unroll
        for (int s = 0; s < 4; ++s) {
            float4 u0 = whh4[n * 32 + s * 8 + q * 2];
            float4 u1 = whh4[n * 32 + s * 8 + q * 2 + 1];
            wf[g][s] = cvt8(u0, u1);   // B[k=s*32+q*8+e][n]
        }
    }
    // Kalman-wave weights (meaningful on w0)
    bf16x8 fcf[4];
    #pragma unroll
    for (int s = 0; s < 4; ++s) {
        float4 u0 = make_float4(0.f, 0.f, 0.f, 0.f), u1 = u0;
        if (idx < 10) {
            u0 = ((const float4*)Wfc)[idx * 32 + s * 8 + q * 2];
            u1 = ((const float4*)Wfc)[idx * 32 + s * 8 + q * 2 + 1];
        }
        fcf[s] = cvt8(u0, u1);
    }
    const float bfc_r = (idx < 10) ? bfc[idx] : 0.0f;
    // Qt coefficients for DPP-Qdot: qreg2[c][r] = Qt[4*a4+c][r][j] (0 if n>=10)
    float qreg2[4][4];
    #pragma unroll
    for (int c = 0; c < 4; ++c) {
        const int n = 4 * a4 + c;
        #pragma unroll
        for (int r = 0; r < 4; ++r)
            qreg2[c][r] = (n < 10) ? Qt[n * 16 + r * 4 + j] : 0.0f;
    }

    // ---- persistent state (Kalman parts meaningful on w0 only) ----
    float P0 = (j == 0) ? 1.f : 0.f, P1 = (j == 1) ? 1.f : 0.f;
    float P2 = (j == 2) ? 1.f : 0.f, P3 = (j == 3) ? 1.f : 0.f;
    float x0 = 0.f, x1 = 0.f, x2 = 0.f, x3 = 0.f;
    float cst = 0.f;
    float ppc0, ppc1, ppc2, ppc3, xp0, xp1, inn0, inn1, In0, In1;
    f32x4 acc[4];

    #define PREDICT(TT)                                                          \
    {                                                                            \
        const float fp0 = P0 + DTc * P2, fp1 = P1 + DTc * P3;                    \
        const float d0 = dppf<QP_ROT2>(P0), d1 = dppf<QP_ROT2>(P1);              \
        const float d2 = dppf<QP_ROT2>(P2), d3 = dppf<QP_ROT2>(P3);              \
        const float fq0 = d0 + DTc * d2, fq1 = d1 + DTc * d3;                    \
        const bool jl2 = (j < 2);                                                \
        ppc0 = fp0 + (jl2 ? DTc * fq0 : 0.f) + ((j == 0) ? Q0V : 0.f);           \
        ppc1 = fp1 + (jl2 ? DTc * fq1 : 0.f) + ((j == 1) ? Q0V : 0.f);           \
        ppc2 = P2  + (jl2 ? DTc * d2  : 0.f) + ((j == 2) ? Q0V : 0.f);           \
        ppc3 = P3  + (jl2 ? DTc * d3  : 0.f) + ((j == 3) ? Q0V : 0.f);           \
        xp0 = x0 + DTc * x2; xp1 = x1 + DTc * x3;                                \
        const float2 zz = *(const float2*)&meas_s[q * 1024 + 2 * (TT)];          \
        inn0 = zz.x - xp0; inn1 = zz.y - xp1;                                    \
        const float s000 = dppf<QP_BC0>(ppc0) + RV;                              \
        const float s011 = dppf<QP_BC1>(ppc1) + RV;                              \
        In0 = inn0 * inn0 * rcpf(s000);                                          \
        In1 = inn1 * inn1 * rcpf(s011);                                          \
    }

    __syncthreads();   // meas_s ready

    if (w == 0) {
        PREDICT(0)
        if (idx == 0) inbuf[q] = make_float2(In0, In1);
    }
    #pragma unroll
    for (int g = 0; g < 4; ++g) acc[g] = biasC[g];   // h(-1)=0 -> gates = bias

    __syncthreads();   // inbuf(0) ready

    for (int t = 0; t < 512; ++t) {
        // ======== segment A: pointwise LSTM(t), 1 cell (hh, q) per thread ====
        {
            const float2 inq = inbuf[q];
            float pre[4];
            #pragma unroll
            for (int g = 0; g < 4; ++g)
                pre[g] = acc[g][0] + inq.x * wihr[g].x + inq.y * wihr[g].y;
            const float cn = sigmf(pre[1]) * cst + sigmf(pre[0]) * tanhf_(pre[2]);
            const float hn = sigmf(pre[3]) * tanhf_(cn);
            cst = cn;
            hbuf[q * 160 + hh] = f2bf(hn);
        }
        __syncthreads();   // B1: h(t) published

        // ======== segment B: GEMM everywhere; Kalman tail on w0 (DPP only) ===
        bf16x8 af[4];
        #pragma unroll
        for (int s = 0; s < 4; ++s)
            af[s] = __builtin_bit_cast(bf16x8,
                        *(const uint4*)&hbuf[(idx >> 2) * 160 + s * 32 + q * 8]);

        if (w == 0) {
            // fc GEMM -> sigma (own batch q, n = idx)
            f32x4 f0 = (f32x4){0.f, 0.f, 0.f, 0.f};
            f32x4 f1 = (f32x4){0.f, 0.f, 0.f, 0.f};
            f0 = __builtin_amdgcn_mfma_f32_16x16x32_bf16(af[0], fcf[0], f0, 0, 0, 0);
            f1 = __builtin_amdgcn_mfma_f32_16x16x32_bf16(af[1], fcf[1], f1, 0, 0, 0);
            f0 = __builtin_amdgcn_mfma_f32_16x16x32_bf16(af[2], fcf[2], f0, 0, 0, 0);
            f1 = __builtin_amdgcn_mfma_f32_16x16x32_bf16(af[3], fcf[3], f1, 0, 0, 0);
            const f32x4 facc = f0 + f1;
            const float sg = (idx < 10) ? sigmf(facc[0] + bfc_r) : 0.0f;

            // DPP-Qdot: quad broadcasts -> 16 FMA partials -> rotate-add rounds
            const float s0 = dppf<QP_BC0>(sg), s1 = dppf<QP_BC1>(sg);
            const float s2 = dppf<QP_BC2>(sg), s3 = dppf<QP_BC3>(sg);
            float p0 = s0 * qreg2[0][0] + s1 * qreg2[1][0] + s2 * qreg2[2][0] + s3 * qreg2[3][0];
            float p1 = s0 * qreg2[0][1] + s1 * qreg2[1][1] + s2 * qreg2[2][1] + s3 * qreg2[3][1];
            float p2 = s0 * qreg2[0][2] + s1 * qreg2[1][2] + s2 * qreg2[2][2] + s3 * qreg2[3][2];
            float p3 = s0 * qreg2[0][3] + s1 * qreg2[1][3] + s2 * qreg2[2][3] + s3 * qreg2[3][3];
            p0 += dppf<ROW_ROR4>(p0); p1 += dppf<ROW_ROR4>(p1);
            p2 += dppf<ROW_ROR4>(p2); p3 += dppf<ROW_ROR4>(p3);
            p0 += dppf<ROW_ROR8>(p0); p1 += dppf<ROW_ROR8>(p1);
            p2 += dppf<ROW_ROR8>(p2); p3 += dppf<ROW_ROR8>(p3);

            const float pc0 = ppc0 + p0;   // P_pred[:,j]
            const float pc1 = ppc1 + p1;
            const float pc2 = ppc2 + p2;
            const float pc3 = ppc3 + p3;

            // Kalman update (K eliminated)
            const float ph00 = dppf<QP_BC0>(pc0), ph01 = dppf<QP_BC1>(pc0);
            const float ph10 = dppf<QP_BC0>(pc1), ph11 = dppf<QP_BC1>(pc1);
            const float ph20 = dppf<QP_BC0>(pc2), ph21 = dppf<QP_BC1>(pc2);
            const float ph30 = dppf<QP_BC0>(pc3), ph31 = dppf<QP_BC1>(pc3);
            const float s00 = ph00 + RV, s01 = ph01, s10 = ph10, s11 = ph11 + RV;
            const float rdet = rcpf(s00 * s11 - s01 * s10);
            const float u0 = rdet * (s11 * inn0 - s01 * inn1);
            const float u1 = rdet * (s00 * inn1 - s10 * inn0);
            x0 = xp0 + ph00 * u0 + ph01 * u1;
            x1 = xp1 + ph10 * u0 + ph11 * u1;
            x2 = x2  + ph20 * u0 + ph21 * u1;
            x3 = x3  + ph30 * u0 + ph31 * u1;
            const float w0r = rdet * (s11 * pc0 - s01 * pc1);
            const float w1r = rdet * (s00 * pc1 - s10 * pc0);
            P0 = pc0 - ph00 * w0r - ph01 * w1r;
            P1 = pc1 - ph10 * w0r - ph11 * w1r;
            P2 = pc2 - ph20 * w0r - ph21 * w1r;
            P3 = pc3 - ph30 * w0r - ph31 * w1r;
            if (idx == 0) {
                float4* o = (float4*)out;
                o[(size_t)(bg0 + q) * 512 + t] = make_float4(x0, x1, x2, x3);
            }
            const int tn = (t < 511) ? t + 1 : 511;
            PREDICT(tn)
            if (idx == 0) inbuf[q] = make_float2(In0, In1);
        }

        // recurrent GEMM(t+1), bias in C of first MFMA (all waves)
        #pragma unroll
        for (int g = 0; g < 4; ++g)
            acc[g] = __builtin_amdgcn_mfma_f32_16x16x32_bf16(af[0], wf[g][0], biasC[g], 0, 0, 0);
        #pragma unroll
        for (int s = 1; s < 4; ++s)
            #pragma unroll
            for (int g = 0; g < 4; ++g)
                acc[g] = __builtin_amdgcn_mfma_f32_16x16x32_bf16(af[s], wf[g][s], acc[g], 0, 0, 0);

        __syncthreads();   // B2: In(t+1) published; hbuf free for rewrite
    }
}

extern "C" void kernel_launch(void* const* d_in, const int* in_sizes, int n_in,
                              void* d_out, int out_size, void* d_ws, size_t ws_size,
                              hipStream_t stream) {
    (void)in_sizes; (void)n_in; (void)out_size; (void)d_ws; (void)ws_size;
    nnakf_kernel<<<256, 512, 0, stream>>>(
        (const float*)d_in[0],  // measurements
        (const float*)d_in[1],  // Q_tilde
        (const float*)d_in[2],  // W_ih
        (const float*)d_in[3],  // W_hh
        (const float*)d_in[4],  // b_ih
        (const float*)d_in[5],  // b_hh
        (const float*)d_in[6],  // W_fc
        (const float*)d_in[7],  // b_fc
        (float*)d_out);
}